// Round 11
// baseline (239.780 us; speedup 1.0000x reference)
//
#include <hip/hip_runtime.h>
#include <math.h>

// DeltaNetTemporal: B=16, N=4096, C=256, H=4, D=64.  All I/O fp32.
// R6: state_pass eliminated by linearity (fold+GEMM; v-GEMM eliminated).
// R7/R8: beta_xbsum latency fix: 330.6 -> 286.7 us.
// R9: fold_M re-parallelized: 286.7 -> 250.7 us.
// R10/R11: f16 pre-conversion (xh/Wkh/Wogh): 250.7 -> 235.8.
// R12: gload_lds staging + both-sides swizzle: kgemm off top-5.
// R13: ygemm+ogemm fused (yogemm): 235 -> 225.7.
// R14 REGRESSED (248.7): dual accumulators + extra dispatches. Lesson:
//   occupancy/stall-bound; barriers-vs-registers trade is net-zero.
// R15/R16: yogemm + phase-2-kt0 prefetch + setprio: 225.7 -> 224.3
//   (yogemm 61.5 -> 42.4 us).
// R17: kgemm FUSED into yogemm as phase 0 (same staging/MFMA structure as
//   phase 1, B = Wkh). Epilogue in registers: elu+1, per-(row,head) L2-norm
//   (in-lane + shfl_xor 1..8), col-sums via 16-row partials + shfl_xor(16,32)
//   + atomics. Kills kgemm's dispatch, its 32MB second xh HBM pass, and its
//   half-idle serial LDS epilogue. Phase-1 kt0 A+B prefetched during the
//   register-only k-epilogue (R15 pattern). acc reused sequentially.
// Pipeline: memset -> prep_w -> beta+xbsum(+xh) -> fold M -> kyogemm -> finalize.

typedef _Float16 f16;
typedef f16 f16x8 __attribute__((ext_vector_type(8)));
typedef f16 f16x4 __attribute__((ext_vector_type(4)));
typedef float f32x4 __attribute__((ext_vector_type(4)));

typedef const __attribute__((address_space(1))) void gvoid;
typedef __attribute__((address_space(3))) void svoid;

// async global->LDS, 16B/lane; LDS dest is wave-uniform base + lane*16.
__device__ __forceinline__ void gload16(const void* g, void* l) {
  __builtin_amdgcn_global_load_lds((gvoid*)g, (svoid*)l, 16, 0, 0);
}

__device__ __forceinline__ f16x8 cvt8(const float* q) {
  float4 a = *(const float4*)q;
  float4 b = *(const float4*)(q + 4);
  f16x8 r;
  r[0] = (f16)a.x; r[1] = (f16)a.y; r[2] = (f16)a.z; r[3] = (f16)a.w;
  r[4] = (f16)b.x; r[5] = (f16)b.y; r[6] = (f16)b.z; r[7] = (f16)b.w;
  return r;
}

// ---------------- prep: Wkh = f16(Wk); Wogh = f16(Wo * g) ----------------
__global__ __launch_bounds__(256) void prep_w(
    const float* __restrict__ Wk, const float* __restrict__ Wo,
    const float* __restrict__ g, f16* __restrict__ Wkh,
    f16* __restrict__ Wogh) {
  int i = blockIdx.x * 256 + threadIdx.x;  // grid 64 -> 16384 threads
#pragma unroll
  for (int j = 0; j < 4; ++j) {
    int idx = i + j * 16384;  // 65536 elements each
    Wkh[idx] = (f16)Wk[idx];
    Wogh[idx] = (f16)(Wo[idx] * g[idx & 255]);
  }
}

// ---------------- beta + xbsum (+ xh store) ----------------
__global__ __launch_bounds__(256) void beta_xbsum_h(
    const float* __restrict__ x, const float* __restrict__ Wb,
    float* __restrict__ betaArr, float* __restrict__ xbsum,
    f16* __restrict__ xh) {
  const int t = threadIdx.x;
  const int wave = t >> 6, lane = t & 63;
  const int b = blockIdx.x >> 6;
  const int tile = blockIdx.x & 63;
  float4 wb[4];
#pragma unroll
  for (int h = 0; h < 4; ++h) wb[h] = *(const float4*)(Wb + h * 256 + lane * 4);
  float xacc[4][4] = {};
  const size_t rowbase = (size_t)b * 4096 + tile * 64;
  __shared__ float bsh[4][64];
  float4 xv = *(const float4*)(x + (rowbase + wave) * 256 + lane * 4);
#pragma unroll 2
  for (int i = 0; i < 16; ++i) {
    int r = i * 4 + wave;
    float4 nx = xv;
    if (i < 15)
      nx = *(const float4*)(x + (rowbase + r + 4) * 256 + lane * 4);
    f16x4 hx;
    hx[0] = (f16)xv.x; hx[1] = (f16)xv.y; hx[2] = (f16)xv.z; hx[3] = (f16)xv.w;
    *(f16x4*)(xh + (rowbase + r) * 256 + lane * 4) = hx;
#pragma unroll
    for (int h = 0; h < 4; ++h) {
      float s = xv.x * wb[h].x + xv.y * wb[h].y + xv.z * wb[h].z + xv.w * wb[h].w;
#pragma unroll
      for (int off = 32; off; off >>= 1) s += __shfl_xor(s, off);
      float bh = 1.f / (1.f + __expf(-s));
      if (lane == h) bsh[h][r] = bh;
      xacc[h][0] += bh * xv.x; xacc[h][1] += bh * xv.y;
      xacc[h][2] += bh * xv.z; xacc[h][3] += bh * xv.w;
    }
    xv = nx;
  }
  __shared__ float xbp[4][4][256];
#pragma unroll
  for (int h = 0; h < 4; ++h)
#pragma unroll
    for (int j = 0; j < 4; ++j) xbp[wave][h][lane * 4 + j] = xacc[h][j];
  __syncthreads();
  {
    int h = t >> 6, r = t & 63;
    betaArr[((size_t)(b * 4 + h) << 12) + tile * 64 + r] = bsh[h][r];
  }
  for (int idx = t; idx < 1024; idx += 256) {
    int h = idx >> 8, c = idx & 255;
    float s = xbp[0][h][c] + xbp[1][h][c] + xbp[2][h][c] + xbp[3][h][c];
    atomicAdd(&xbsum[(b * 4 + h) * 256 + c], s);
  }
}

// ---------------- fold: M[b][(h,d)][c] = 0.95 * S[b,h] @ Wq_h --------------
__global__ __launch_bounds__(256) void fold_M(
    const float* __restrict__ S, const float* __restrict__ Wq,
    f16* __restrict__ M) {
  const int bh = blockIdx.y;
  const int dq = blockIdx.x;
  const int h = bh & 3;
  const int t = threadIdx.x;
  const float* Sp = S + (size_t)bh * 4096 + dq * 8 * 64;
  const float* Wp = Wq + (size_t)h * 64 * 256 + t;
  float m[8] = {};
#pragma unroll 4
  for (int e = 0; e < 64; ++e) {
    float wv = Wp[e * 256];
#pragma unroll
    for (int dd = 0; dd < 8; ++dd) m[dd] += Sp[dd * 64 + e] * wv;
  }
  f16* Mb = M + (size_t)(bh >> 2) * 65536;
#pragma unroll
  for (int dd = 0; dd < 8; ++dd)
    Mb[(size_t)(h * 64 + dq * 8 + dd) * 256 + t] = (f16)(0.95f * m[dd]);
}

// ---------------- fused k + y + out GEMM ----------------
// Block: 64 rows x 256 cols; wave w owns cols/head w*64..+63 in all phases.
// Phase 0: k = xh@Wkh^T -> elu+1, L2-norm per (row,head), col-sum atomics
//   to ksum/kbsum (all in registers).
// Phase 1: y = xh@M^T (kt0 tiles prefetched during k-epilogue); cross-wave
//   rowssq -> rs; normalized f16 y-tile to swizzled LDS.
// Phase 2: out = yhat@(Wo*g)^T (kt0 Wog prefetched during ssq).
__global__ __launch_bounds__(256) void kyogemm_h(
    const f16* __restrict__ xh, const f16* __restrict__ Wkh,
    const f16* __restrict__ M, const f16* __restrict__ Wogh,
    const float* __restrict__ betaArr, float* __restrict__ ksum,
    float* __restrict__ kbsum, float* __restrict__ out) {
  __shared__ f16 Bst[256 * 64];   // 32 KB: Wk (ph0) / M (ph1) / Wog (ph2)
  __shared__ f16 Ast[64 * 64];    // 8 KB: xh-tile
  __shared__ f16 yl[64 * 256];    // 32 KB: normalized y, chunk^=(row&7)
  __shared__ float ssq[4][64];
  __shared__ float rs_l[64];
  __shared__ float bstage[4][64]; // beta for the block's 64 rows x 4 heads
  const int t = threadIdx.x;
  const int m0 = blockIdx.x * 64;
  const int b = m0 >> 12;
  const f16* Mb = M + (size_t)b * 65536;
  const int wave = t >> 6, lane = t & 63;
  const int wn = wave * 64;
  const int fr = lane & 15, fq = lane >> 4;
  const int fr7 = fr & 7;
  const int srow = lane >> 3;
  const int sc = (lane & 7) ^ srow;
  const char* Ab = (const char*)Ast;
  const char* Bb = (const char*)Bst;
  // stage beta rows (read in phase-0 epilogue, after several barriers)
  bstage[t >> 6][t & 63] =
      betaArr[((size_t)(b * 4 + (t >> 6)) << 12) + (m0 & 4095) + (t & 63)];
  f32x4 acc[4][4] = {};
  // ---- phase 0: k = xh @ Wkh^T ----
#pragma unroll 1
  for (int kt = 0; kt < 4; ++kt) {
    const int k0 = kt * 64;
#pragma unroll
    for (int j = 0; j < 2; ++j) {
      int c = j * 4 + wave;
      int row = c * 8 + srow;
      gload16(xh + (size_t)(m0 + row) * 256 + k0 + sc * 8, Ast + c * 512);
    }
#pragma unroll
    for (int j = 0; j < 8; ++j) {
      int c = j * 4 + wave;
      int row = c * 8 + srow;
      gload16(Wkh + (size_t)row * 256 + k0 + sc * 8, Bst + c * 512);
    }
    __syncthreads();
    __builtin_amdgcn_s_setprio(1);
#pragma unroll
    for (int ks = 0; ks < 2; ++ks) {
      const int p = ((ks * 4 + fq) ^ fr7) << 4;
      f16x8 afr[4], bfr[4];
#pragma unroll
      for (int mi = 0; mi < 4; ++mi)
        afr[mi] = *(const f16x8*)(Ab + (mi * 16 + fr) * 128 + p);
#pragma unroll
      for (int ni = 0; ni < 4; ++ni)
        bfr[ni] = *(const f16x8*)(Bb + (wn + ni * 16 + fr) * 128 + p);
#pragma unroll
      for (int mi = 0; mi < 4; ++mi)
#pragma unroll
        for (int ni = 0; ni < 4; ++ni)
          acc[mi][ni] = __builtin_amdgcn_mfma_f32_16x16x32_f16(
              afr[mi], bfr[ni], acc[mi][ni], 0, 0, 0);
    }
    __builtin_amdgcn_s_setprio(0);
    __syncthreads();
  }
  // ---- prefetch phase-1 kt0 tiles (Ast/Bst free past final barrier) ----
#pragma unroll
  for (int j = 0; j < 2; ++j) {
    int c = j * 4 + wave;
    int row = c * 8 + srow;
    gload16(xh + (size_t)(m0 + row) * 256 + sc * 8, Ast + c * 512);
  }
#pragma unroll
  for (int j = 0; j < 8; ++j) {
    int c = j * 4 + wave;
    int row = c * 8 + srow;
    gload16(Mb + (size_t)row * 256 + sc * 8, Bst + c * 512);
  }
  // ---- k epilogue (registers only): elu+1, L2-norm per (row,head) ----
#pragma unroll
  for (int mi = 0; mi < 4; ++mi)
#pragma unroll
    for (int rr = 0; rr < 4; ++rr) {
      float s = 0.f;
#pragma unroll
      for (int ni = 0; ni < 4; ++ni) {
        float v = acc[mi][ni][rr];
        v = v > 0.f ? v + 1.f : __expf(v);
        acc[mi][ni][rr] = v;
        s += v * v;
      }
#pragma unroll
      for (int off = 1; off < 16; off <<= 1) s += __shfl_xor(s, off);
      float inv = 1.f / (sqrtf(s) + 1e-6f);
#pragma unroll
      for (int ni = 0; ni < 4; ++ni) acc[mi][ni][rr] *= inv;
    }
  // ---- col sums: per-lane 16-row partials, reduce across fq, atomics ----
  {
    float sk[4] = {}, skb[4] = {};
#pragma unroll
    for (int mi = 0; mi < 4; ++mi)
#pragma unroll
      for (int rr = 0; rr < 4; ++rr) {
        int row = mi * 16 + fq * 4 + rr;
        float be = bstage[wave][row];
#pragma unroll
        for (int ni = 0; ni < 4; ++ni) {
          float v = acc[mi][ni][rr];
          sk[ni] += v;
          skb[ni] += be * v;
        }
      }
#pragma unroll
    for (int ni = 0; ni < 4; ++ni) {
#pragma unroll
      for (int off = 16; off < 64; off <<= 1) {
        sk[ni] += __shfl_xor(sk[ni], off);
        skb[ni] += __shfl_xor(skb[ni], off);
      }
    }
    if (fq == 0) {
      int gh = b * 4 + wave;
#pragma unroll
      for (int ni = 0; ni < 4; ++ni) {
        atomicAdd(&ksum[gh * 64 + ni * 16 + fr], sk[ni]);
        atomicAdd(&kbsum[gh * 64 + ni * 16 + fr], skb[ni]);
      }
    }
  }
  __syncthreads();  // drains prefetch vmcnt; all waves aligned for phase 1
  // ---- phase 1: y = xh @ M^T (kt0 already staged) ----
#pragma unroll
  for (int mi = 0; mi < 4; ++mi)
#pragma unroll
    for (int ni = 0; ni < 4; ++ni) acc[mi][ni] = (f32x4){0.f, 0.f, 0.f, 0.f};
#pragma unroll 1
  for (int kt = 0; kt < 4; ++kt) {
    if (kt > 0) {
      const int k0 = kt * 64;
#pragma unroll
      for (int j = 0; j < 2; ++j) {
        int c = j * 4 + wave;
        int row = c * 8 + srow;
        gload16(xh + (size_t)(m0 + row) * 256 + k0 + sc * 8, Ast + c * 512);
      }
#pragma unroll
      for (int j = 0; j < 8; ++j) {
        int c = j * 4 + wave;
        int row = c * 8 + srow;
        gload16(Mb + (size_t)row * 256 + k0 + sc * 8, Bst + c * 512);
      }
      __syncthreads();
    }
    __builtin_amdgcn_s_setprio(1);
#pragma unroll
    for (int ks = 0; ks < 2; ++ks) {
      const int p = ((ks * 4 + fq) ^ fr7) << 4;
      f16x8 afr[4], bfr[4];
#pragma unroll
      for (int mi = 0; mi < 4; ++mi)
        afr[mi] = *(const f16x8*)(Ab + (mi * 16 + fr) * 128 + p);
#pragma unroll
      for (int ni = 0; ni < 4; ++ni)
        bfr[ni] = *(const f16x8*)(Bb + (wn + ni * 16 + fr) * 128 + p);
#pragma unroll
      for (int mi = 0; mi < 4; ++mi)
#pragma unroll
        for (int ni = 0; ni < 4; ++ni)
          acc[mi][ni] = __builtin_amdgcn_mfma_f32_16x16x32_f16(
              afr[mi], bfr[ni], acc[mi][ni], 0, 0, 0);
    }
    __builtin_amdgcn_s_setprio(0);
    __syncthreads();
  }
  // ---- prefetch phase-2 kt0 Wog tile ----
#pragma unroll
  for (int j = 0; j < 8; ++j) {
    int c = j * 4 + wave;
    int row = c * 8 + srow;
    gload16(Wogh + (size_t)row * 256 + sc * 8, Bst + c * 512);
  }
  // ---- rowssq across 4 waves ----
#pragma unroll
  for (int mi = 0; mi < 4; ++mi)
#pragma unroll
    for (int rr = 0; rr < 4; ++rr) {
      float s = 0.f;
#pragma unroll
      for (int ni = 0; ni < 4; ++ni) {
        float v = acc[mi][ni][rr];
        s += v * v;
      }
#pragma unroll
      for (int off = 1; off < 16; off <<= 1) s += __shfl_xor(s, off);
      if (fr == 0) ssq[wave][mi * 16 + fq * 4 + rr] = s;
    }
  __syncthreads();
  if (t < 64)
    rs_l[t] = rsqrtf((ssq[0][t] + ssq[1][t] + ssq[2][t] + ssq[3][t]) *
                         (1.f / 256.f) +
                     1e-6f);
  __syncthreads();
  // ---- normalize + write swizzled f16 y-tile ----
#pragma unroll
  for (int mi = 0; mi < 4; ++mi)
#pragma unroll
    for (int rr = 0; rr < 4; ++rr) {
      int row = mi * 16 + fq * 4 + rr;
      float rs = rs_l[row];
      int r7 = row & 7;
#pragma unroll
      for (int ni = 0; ni < 4; ++ni) {
        int col = wn + ni * 16 + fr;
        int idx = row * 256 + ((((col >> 3) ^ r7) << 3) | (col & 7));
        yl[idx] = (f16)(rs * acc[mi][ni][rr]);
      }
    }
  __syncthreads();
  // ---- phase 2: out = yhat @ Wog^T (kt0 tile already staged) ----
#pragma unroll
  for (int mi = 0; mi < 4; ++mi)
#pragma unroll
    for (int ni = 0; ni < 4; ++ni) acc[mi][ni] = (f32x4){0.f, 0.f, 0.f, 0.f};
#pragma unroll 1
  for (int kt = 0; kt < 4; ++kt) {
    if (kt > 0) {
      const int k0 = kt * 64;
#pragma unroll
      for (int j = 0; j < 8; ++j) {
        int c = j * 4 + wave;
        int row = c * 8 + srow;
        gload16(Wogh + (size_t)row * 256 + k0 + sc * 8, Bst + c * 512);
      }
      __syncthreads();
    }
    __builtin_amdgcn_s_setprio(1);
#pragma unroll
    for (int ks = 0; ks < 2; ++ks) {
      const int p = ((ks * 4 + fq) ^ fr7) << 4;
      f16x8 afr[4], bfr[4];
#pragma unroll
      for (int mi = 0; mi < 4; ++mi) {
        int row = mi * 16 + fr;
        int chunk = ((kt * 8 + ks * 4 + fq) ^ (row & 7)) << 4;
        afr[mi] = *(const f16x8*)((const char*)yl + row * 512 + chunk);
      }
#pragma unroll
      for (int ni = 0; ni < 4; ++ni)
        bfr[ni] = *(const f16x8*)(Bb + (wn + ni * 16 + fr) * 128 + p);
#pragma unroll
      for (int mi = 0; mi < 4; ++mi)
#pragma unroll
        for (int ni = 0; ni < 4; ++ni)
          acc[mi][ni] = __builtin_amdgcn_mfma_f32_16x16x32_f16(
              afr[mi], bfr[ni], acc[mi][ni], 0, 0, 0);
    }
    __builtin_amdgcn_s_setprio(0);
    __syncthreads();
  }
#pragma unroll
  for (int mi = 0; mi < 4; ++mi)
#pragma unroll
    for (int ni = 0; ni < 4; ++ni)
#pragma unroll
      for (int rr = 0; rr < 4; ++rr) {
        int row = m0 + mi * 16 + fq * 4 + rr;
        int col = wn + ni * 16 + fr;
        out[(size_t)row * 256 + col] = acc[mi][ni][rr];
      }
}

// ================= R9 fallback path (fp32 staging) =================
__global__ __launch_bounds__(256) void beta_xbsum(
    const float* __restrict__ x, const float* __restrict__ Wb,
    float* __restrict__ betaArr, float* __restrict__ xbsum) {
  const int t = threadIdx.x;
  const int wave = t >> 6, lane = t & 63;
  const int b = blockIdx.x >> 6;
  const int tile = blockIdx.x & 63;
  float4 wb[4];
#pragma unroll
  for (int h = 0; h < 4; ++h) wb[h] = *(const float4*)(Wb + h * 256 + lane * 4);
  float xacc[4][4] = {};
  const size_t rowbase = (size_t)b * 4096 + tile * 64;
  __shared__ float bsh[4][64];
  float4 xv = *(const float4*)(x + (rowbase + wave) * 256 + lane * 4);
#pragma unroll 2
  for (int i = 0; i < 16; ++i) {
    int r = i * 4 + wave;
    float4 nx = xv;
    if (i < 15)
      nx = *(const float4*)(x + (rowbase + r + 4) * 256 + lane * 4);
#pragma unroll
    for (int h = 0; h < 4; ++h) {
      float s = xv.x * wb[h].x + xv.y * wb[h].y + xv.z * wb[h].z + xv.w * wb[h].w;
#pragma unroll
      for (int off = 32; off; off >>= 1) s += __shfl_xor(s, off);
      float bh = 1.f / (1.f + __expf(-s));
      if (lane == h) bsh[h][r] = bh;
      xacc[h][0] += bh * xv.x; xacc[h][1] += bh * xv.y;
      xacc[h][2] += bh * xv.z; xacc[h][3] += bh * xv.w;
    }
    xv = nx;
  }
  __shared__ float xbp[4][4][256];
#pragma unroll
  for (int h = 0; h < 4; ++h)
#pragma unroll
    for (int j = 0; j < 4; ++j) xbp[wave][h][lane * 4 + j] = xacc[h][j];
  __syncthreads();
  {
    int h = t >> 6, r = t & 63;
    betaArr[((size_t)(b * 4 + h) << 12) + tile * 64 + r] = bsh[h][r];
  }
  for (int idx = t; idx < 1024; idx += 256) {
    int h = idx >> 8, c = idx & 255;
    float s = xbp[0][h][c] + xbp[1][h][c] + xbp[2][h][c] + xbp[3][h][c];
    atomicAdd(&xbsum[(b * 4 + h) * 256 + c], s);
  }
}

__global__ __launch_bounds__(256) void kgemm_sums(
    const float* __restrict__ x, const float* __restrict__ Wk,
    const float* __restrict__ betaArr,
    float* __restrict__ ksum, float* __restrict__ kbsum) {
  __shared__ union {
    struct { f16 A[128][72]; f16 B[128][72]; } s;
    f16 K[128][132];
  } u;
  __shared__ float bstage[2][128];
  const int t = threadIdx.x;
  const int m0 = blockIdx.y * 128;
  const int n0 = blockIdx.x * 128;
  const int b = m0 >> 12;
  const int wave = t >> 6, lane = t & 63;
  const int wm = (wave >> 1) * 64, wn = (wave & 1) * 64;
  const int fr = lane & 15, fq = lane >> 4;
  {
    int hh = t >> 7, r = t & 127;
    bstage[hh][r] =
        betaArr[((size_t)(b * 4 + (n0 >> 6) + hh) << 12) + (m0 & 4095) + r];
  }
  f32x4 acc[4][4] = {};
#pragma unroll 1
  for (int kt = 0; kt < 4; ++kt) {
    const int k0 = kt * 64;
#pragma unroll
    for (int i = 0; i < 4; ++i) {
      int id = i * 256 + t;
      int row = id >> 3, cc = id & 7;
      *(f16x8*)&u.s.A[row][cc * 8] =
          cvt8(x + (size_t)(m0 + row) * 256 + k0 + cc * 8);
      *(f16x8*)&u.s.B[row][cc * 8] =
          cvt8(Wk + (size_t)(n0 + row) * 256 + k0 + cc * 8);
    }
    __syncthreads();
#pragma unroll
    for (int ks = 0; ks < 2; ++ks) {
      f16x8 afr[4], bfr[4];
#pragma unroll
      for (int mi = 0; mi < 4; ++mi)
        afr[mi] = *(const f16x8*)&u.s.A[wm + mi * 16 + fr][ks * 32 + fq * 8];
#pragma unroll
      for (int ni = 0; ni < 4; ++ni)
        bfr[ni] = *(const f16x8*)&u.s.B[wn + ni * 16 + fr][ks * 32 + fq * 8];
#pragma unroll
      for (int mi = 0; mi < 4; ++mi)
#pragma unroll
        for (int ni = 0; ni < 4; ++ni)
          acc[mi][ni] = __builtin_amdgcn_mfma_f32_16x16x32_f16(
              afr[mi], bfr[ni], acc[mi][ni], 0, 0, 0);
    }
    __syncthreads();
  }
#pragma unroll
  for (int mi = 0; mi < 4; ++mi)
#pragma unroll
    for (int rr = 0; rr < 4; ++rr) {
      float s = 0.f;
#pragma unroll
      for (int ni = 0; ni < 4; ++ni) {
        float v = acc[mi][ni][rr];
        v = v > 0.f ? v + 1.f : __expf(v);
        acc[mi][ni][rr] = v;
        s += v * v;
      }
#pragma unroll
      for (int off = 1; off < 16; off <<= 1) s += __shfl_xor(s, off);
      float inv = 1.f / (sqrtf(s) + 1e-6f);
#pragma unroll
      for (int ni = 0; ni < 4; ++ni) acc[mi][ni][rr] *= inv;
    }
#pragma unroll
  for (int mi = 0; mi < 4; ++mi)
#pragma unroll
    for (int ni = 0; ni < 4; ++ni)
#pragma unroll
      for (int rr = 0; rr < 4; ++rr)
        u.K[wm + mi * 16 + fq * 4 + rr][wn + ni * 16 + fr] = (f16)acc[mi][ni][rr];
  __syncthreads();
  if (t < 128) {
    const int c = t, hl = c >> 6;
    float sk = 0.f, skb = 0.f;
#pragma unroll 4
    for (int r = 0; r < 128; ++r) {
      float v = (float)u.K[r][c];
      float be = bstage[hl][r];
      sk += v;
      skb += be * v;
    }
    int gh = b * 4 + (n0 >> 6) + hl;
    atomicAdd(&ksum[gh * 64 + (c & 63)], sk);
    atomicAdd(&kbsum[gh * 64 + (c & 63)], skb);
  }
}

__global__ __launch_bounds__(256) void ygemm_ssq(
    const float* __restrict__ x, int m_base, const f16* __restrict__ M,
    f16* __restrict__ y, float* __restrict__ rowssq) {
  __shared__ f16 As[128][72];
  __shared__ f16 Bs[128][72];
  const int t = threadIdx.x;
  const int m0 = blockIdx.y * 128;
  const int n0 = blockIdx.x * 128;
  const int b = (m_base + m0) >> 12;
  const f16* Mb = M + (size_t)b * 65536;
  const int wave = t >> 6, lane = t & 63;
  const int wm = (wave >> 1) * 64, wn = (wave & 1) * 64;
  const int fr = lane & 15, fq = lane >> 4;
  f32x4 acc[4][4] = {};
#pragma unroll 1
  for (int kt = 0; kt < 4; ++kt) {
    const int k0 = kt * 64;
#pragma unroll
    for (int i = 0; i < 4; ++i) {
      int id = i * 256 + t;
      int row = id >> 3, cc = id & 7;
      *(f16x8*)&As[row][cc * 8] =
          cvt8(x + (size_t)(m_base + m0 + row) * 256 + k0 + cc * 8);
      *(uint4*)&Bs[row][cc * 8] =
          *(const uint4*)(Mb + (size_t)(n0 + row) * 256 + k0 + cc * 8);
    }
    __syncthreads();
#pragma unroll
    for (int ks = 0; ks < 2; ++ks) {
      f16x8 afr[4], bfr[4];
#pragma unroll
      for (int mi = 0; mi < 4; ++mi)
        afr[mi] = *(const f16x8*)&As[wm + mi * 16 + fr][ks * 32 + fq * 8];
#pragma unroll
      for (int ni = 0; ni < 4; ++ni)
        bfr[ni] = *(const f16x8*)&Bs[wn + ni * 16 + fr][ks * 32 + fq * 8];
#pragma unroll
      for (int mi = 0; mi < 4; ++mi)
#pragma unroll
        for (int ni = 0; ni < 4; ++ni)
          acc[mi][ni] = __builtin_amdgcn_mfma_f32_16x16x32_f16(
              afr[mi], bfr[ni], acc[mi][ni], 0, 0, 0);
    }
    __syncthreads();
  }
#pragma unroll
  for (int mi = 0; mi < 4; ++mi)
#pragma unroll
    for (int rr = 0; rr < 4; ++rr) {
      float s = 0.f;
#pragma unroll
      for (int ni = 0; ni < 4; ++ni) {
        float v = acc[mi][ni][rr];
        s += v * v;
        int row = m0 + wm + mi * 16 + fq * 4 + rr;
        int col = n0 + wn + ni * 16 + fr;
        y[(size_t)row * 256 + col] = (f16)v;
      }
#pragma unroll
      for (int off = 1; off < 16; off <<= 1) s += __shfl_xor(s, off);
      if (fr == 0)
        atomicAdd(&rowssq[m0 + wm + mi * 16 + fq * 4 + rr], s);
    }
}

__global__ __launch_bounds__(256) void ogemm_scaled(
    const f16* __restrict__ y, const float* __restrict__ rowssq,
    const float* __restrict__ g_rms, const float* __restrict__ Wo,
    float* __restrict__ out, int m_base) {
  __shared__ f16 As[128][72];
  __shared__ f16 Bs[128][72];
  const int t = threadIdx.x;
  const int m0 = blockIdx.y * 128;
  const int n0 = blockIdx.x * 128;
  const int wave = t >> 6, lane = t & 63;
  const int wm = (wave >> 1) * 64, wn = (wave & 1) * 64;
  const int fr = lane & 15, fq = lane >> 4;
  f32x4 acc[4][4] = {};
#pragma unroll 1
  for (int kt = 0; kt < 4; ++kt) {
    const int k0 = kt * 64;
#pragma unroll
    for (int i = 0; i < 4; ++i) {
      int id = i * 256 + t;
      int row = id >> 3, cc = id & 7;
      float rs = rsqrtf(rowssq[m0 + row] * (1.f / 256.f) + 1e-6f);
      const f16* yp = y + (size_t)(m0 + row) * 256 + k0 + cc * 8;
      const float* gp = g_rms + k0 + cc * 8;
      f16x8 a;
#pragma unroll
      for (int j = 0; j < 8; ++j) a[j] = (f16)((float)yp[j] * rs * gp[j]);
      *(f16x8*)&As[row][cc * 8] = a;
      *(f16x8*)&Bs[row][cc * 8] =
          cvt8(Wo + (size_t)(n0 + row) * 256 + k0 + cc * 8);
    }
    __syncthreads();
#pragma unroll
    for (int ks = 0; ks < 2; ++ks) {
      f16x8 afr[4], bfr[4];
#pragma unroll
      for (int mi = 0; mi < 4; ++mi)
        afr[mi] = *(const f16x8*)&As[wm + mi * 16 + fr][ks * 32 + fq * 8];
#pragma unroll
      for (int ni = 0; ni < 4; ++ni)
        bfr[ni] = *(const f16x8*)&Bs[wn + ni * 16 + fr][ks * 32 + fq * 8];
#pragma unroll
      for (int mi = 0; mi < 4; ++mi)
#pragma unroll
        for (int ni = 0; ni < 4; ++ni)
          acc[mi][ni] = __builtin_amdgcn_mfma_f32_16x16x32_f16(
              afr[mi], bfr[ni], acc[mi][ni], 0, 0, 0);
    }
    __syncthreads();
  }
#pragma unroll
  for (int mi = 0; mi < 4; ++mi)
#pragma unroll
    for (int ni = 0; ni < 4; ++ni)
#pragma unroll
      for (int rr = 0; rr < 4; ++rr) {
        int row = m_base + m0 + wm + mi * 16 + fq * 4 + rr;
        int col = n0 + wn + ni * 16 + fr;
        out[(size_t)row * 256 + col] = acc[mi][ni][rr];
      }
}

// ---------------- finalize S ----------------
__global__ __launch_bounds__(256) void finalize_S(
    const float* __restrict__ S, const float* __restrict__ Wv,
    const float* __restrict__ xbsum, const float* __restrict__ ksum,
    const float* __restrict__ kbsum, float* __restrict__ Sout) {
  const int bh = blockIdx.x;
  const int h = bh & 3;
  const int t = threadIdx.x;
  const int wave = t >> 6, lane = t & 63;
  __shared__ float xb[256], kb[64], key[64], errv[64];
  xb[t] = xbsum[bh * 256 + t];
  if (t < 64) {
    kb[t] = kbsum[bh * 64 + t];
    key[t] = ksum[bh * 64 + t] * (1.f / 4096.f);
  }
  __syncthreads();
#pragma unroll 1
  for (int ri = 0; ri < 16; ++ri) {
    int i = wave * 16 + ri;
    float4 wv4 = *(const float4*)(Wv + (size_t)(h * 64 + i) * 256 + lane * 4);
    float4 xb4 = *(const float4*)(&xb[lane * 4]);
    float s = wv4.x * xb4.x + wv4.y * xb4.y + wv4.z * xb4.z + wv4.w * xb4.w;
    s -= 0.95f * S[(size_t)bh * 4096 + i * 64 + lane] * kb[lane];
#pragma unroll
    for (int off = 32; off; off >>= 1) s += __shfl_xor(s, off);
    if (lane == 0) errv[i] = s * (1.f / 4096.f);
  }
  __syncthreads();
  for (int idx = t; idx < 4096; idx += 256) {
    int i = idx >> 6, j = idx & 63;
    float v = 0.95f * S[(size_t)bh * 4096 + idx] + errv[i] * key[j];
    Sout[(size_t)bh * 4096 + idx] = fminf(10.f, fmaxf(-10.f, v));
  }
}

extern "C" void kernel_launch(void* const* d_in, const int* in_sizes, int n_in,
                              void* d_out, int out_size, void* d_ws, size_t ws_size,
                              hipStream_t stream) {
  const float* x  = (const float*)d_in[0];
  const float* S  = (const float*)d_in[1];
  const float* Wq = (const float*)d_in[2];
  const float* Wk = (const float*)d_in[3];
  const float* Wv = (const float*)d_in[4];
  const float* Wb = (const float*)d_in[5];
  const float* Wo = (const float*)d_in[6];
  const float* g  = (const float*)d_in[7];

  char* w = (char*)d_ws;
  float* betaArr = (float*)w;                    // 1,048,576 B
  f16*   M       = (f16*)(w + 1048576);          // 2,097,152 B
  f16*   y       = (f16*)(w + 3145728);          // 16,777,216 B (fallback only)
  float* rowssq  = (float*)(w + 19922944);       // 262,144 B (fallback only)
  float* xbsum   = (float*)(w + 20185088);       // 65,536 B
  float* ksum    = (float*)(w + 20250624);       // 16,384 B
  float* kbsum   = (float*)(w + 20267008);       // 16,384 B
  f16*   xh      = (f16*)(w + 20283392);         // 33,554,432 B (65536x256)
  f16*   Wkh     = (f16*)(w + 53837824);         // 131,072 B
  f16*   Wogh    = (f16*)(w + 53968896);         // 131,072 B
  const size_t WS_NEED = 54099968ull;

  float* out  = (float*)d_out;                   // [16,4096,256] fp32
  float* Sout = out + (size_t)16 * 4096 * 256;   // [16,4,64,64]  fp32

  if (ws_size >= WS_NEED) {
    hipMemsetAsync(w + 20185088, 0, 98304, stream);  // xbsum..kbsum
    prep_w<<<64, 256, 0, stream>>>(Wk, Wo, g, Wkh, Wogh);
    beta_xbsum_h<<<1024, 256, 0, stream>>>(x, Wb, betaArr, xbsum, xh);
    fold_M<<<dim3(8, 64), 256, 0, stream>>>(S, Wq, M);
    kyogemm_h<<<1024, 256, 0, stream>>>(xh, Wkh, M, Wogh, betaArr, ksum,
                                        kbsum, out);
  } else {
    hipMemsetAsync(w + 19922944, 0, 360448, stream);  // rowssq..kbsum
    beta_xbsum<<<1024, 256, 0, stream>>>(x, Wb, betaArr, xbsum);
    kgemm_sums<<<dim3(2, 512), 256, 0, stream>>>(x, Wk, betaArr, ksum, kbsum);
    fold_M<<<dim3(8, 64), 256, 0, stream>>>(S, Wq, M);
    for (int half = 0; half < 2; ++half) {
      int m_base = half * 32768;
      ygemm_ssq<<<dim3(2, 256), 256, 0, stream>>>(x, m_base, M, y,
                                                  rowssq + half * 32768);
      ogemm_scaled<<<dim3(2, 256), 256, 0, stream>>>(y, rowssq + half * 32768,
                                                     g, Wo, out, m_base);
    }
  }
  finalize_S<<<64, 256, 0, stream>>>(S, Wv, xbsum, ksum, kbsum, Sout);
}

// Round 12
// 208.336 us; speedup vs baseline: 1.1509x; 1.1509x over previous
//
#include <hip/hip_runtime.h>
#include <math.h>

// DeltaNetTemporal: B=16, N=4096, C=256, H=4, D=64.  All I/O fp32.
// R6: state_pass eliminated by linearity (fold+GEMM; v-GEMM eliminated).
// R7/R8: beta_xbsum latency fix: 330.6 -> 286.7 us.
// R9: fold_M re-parallelized: 286.7 -> 250.7 us.
// R10/R11: f16 pre-conversion (xh/Wkh/Wogh): 250.7 -> 235.8.
// R12: gload_lds staging + both-sides swizzle: kgemm off top-5.
// R13: ygemm+ogemm fused (yogemm): 235 -> 225.7.
// R14 REGRESSED (248.7): dual accumulators. R17 REGRESSED (239.8): k-phase
//   fusion pushed VGPR 108->152, occupancy 17->10.8%, kyogemm 94us ~= parts.
//   RULE: this family is occupancy-bound at 2 blocks/CU; VGPR>~110 or extra
//   accumulator state is net-negative. No 3-phase mega-fusion.
// R15/R16 (VERIFIED 224.3): yogemm + phase-2-kt0 prefetch + setprio
//   (yogemm 61.5 -> 42.4 us). kgemm_h/yogemm_h below are byte-identical R16.
// R18: revert to R16 + merge the three INDEPENDENT front kernels
//   (prep_w 64blk | beta_xbsum_h 1024blk | fold_M 512blk) into ONE
//   1600-block dispatch (branch on blockIdx.x; per-block uniform).
//   Removes 2 launch ramps; fold/prep hide in beta's memory-bound phase.
// Pipeline: memset -> prep_beta_fold -> kGEMM -> yogemm -> finalize.

typedef _Float16 f16;
typedef f16 f16x8 __attribute__((ext_vector_type(8)));
typedef f16 f16x4 __attribute__((ext_vector_type(4)));
typedef float f32x4 __attribute__((ext_vector_type(4)));

typedef const __attribute__((address_space(1))) void gvoid;
typedef __attribute__((address_space(3))) void svoid;

// async global->LDS, 16B/lane; LDS dest is wave-uniform base + lane*16.
__device__ __forceinline__ void gload16(const void* g, void* l) {
  __builtin_amdgcn_global_load_lds((gvoid*)g, (svoid*)l, 16, 0, 0);
}

__device__ __forceinline__ f16x8 cvt8(const float* q) {
  float4 a = *(const float4*)q;
  float4 b = *(const float4*)(q + 4);
  f16x8 r;
  r[0] = (f16)a.x; r[1] = (f16)a.y; r[2] = (f16)a.z; r[3] = (f16)a.w;
  r[4] = (f16)b.x; r[5] = (f16)b.y; r[6] = (f16)b.z; r[7] = (f16)b.w;
  return r;
}

// ---------------- merged prep_w | beta+xbsum(+xh) | fold_M ----------------
// blocks [0,1024): beta;  [1024,1088): prep_w;  [1088,1600): fold_M.
// All three are mutually independent (disjoint inputs/outputs).
__global__ __launch_bounds__(256) void prep_beta_fold(
    const float* __restrict__ x, const float* __restrict__ S,
    const float* __restrict__ Wq, const float* __restrict__ Wk,
    const float* __restrict__ Wo, const float* __restrict__ Wb,
    const float* __restrict__ g, float* __restrict__ betaArr,
    float* __restrict__ xbsum, f16* __restrict__ xh, f16* __restrict__ Wkh,
    f16* __restrict__ Wogh, f16* __restrict__ M) {
  const int bx_ = blockIdx.x;
  const int t = threadIdx.x;
  if (bx_ < 1024) {
    // ---- beta + xbsum + xh (R16 beta_xbsum_h body) ----
    const int wave = t >> 6, lane = t & 63;
    const int b = bx_ >> 6;
    const int tile = bx_ & 63;
    float4 wb[4];
#pragma unroll
    for (int h = 0; h < 4; ++h)
      wb[h] = *(const float4*)(Wb + h * 256 + lane * 4);
    float xacc[4][4] = {};
    const size_t rowbase = (size_t)b * 4096 + tile * 64;
    __shared__ float bsh[4][64];
    float4 xv = *(const float4*)(x + (rowbase + wave) * 256 + lane * 4);
#pragma unroll 2
    for (int i = 0; i < 16; ++i) {
      int r = i * 4 + wave;
      float4 nx = xv;
      if (i < 15)
        nx = *(const float4*)(x + (rowbase + r + 4) * 256 + lane * 4);
      f16x4 hx;
      hx[0] = (f16)xv.x; hx[1] = (f16)xv.y; hx[2] = (f16)xv.z; hx[3] = (f16)xv.w;
      *(f16x4*)(xh + (rowbase + r) * 256 + lane * 4) = hx;
#pragma unroll
      for (int h = 0; h < 4; ++h) {
        float s = xv.x * wb[h].x + xv.y * wb[h].y + xv.z * wb[h].z +
                  xv.w * wb[h].w;
#pragma unroll
        for (int off = 32; off; off >>= 1) s += __shfl_xor(s, off);
        float bh = 1.f / (1.f + __expf(-s));
        if (lane == h) bsh[h][r] = bh;
        xacc[h][0] += bh * xv.x; xacc[h][1] += bh * xv.y;
        xacc[h][2] += bh * xv.z; xacc[h][3] += bh * xv.w;
      }
      xv = nx;
    }
    __shared__ float xbp[4][4][256];
#pragma unroll
    for (int h = 0; h < 4; ++h)
#pragma unroll
      for (int j = 0; j < 4; ++j) xbp[wave][h][lane * 4 + j] = xacc[h][j];
    __syncthreads();
    {
      int h = t >> 6, r = t & 63;
      betaArr[((size_t)(b * 4 + h) << 12) + tile * 64 + r] = bsh[h][r];
    }
    for (int idx = t; idx < 1024; idx += 256) {
      int h = idx >> 8, c = idx & 255;
      float s = xbp[0][h][c] + xbp[1][h][c] + xbp[2][h][c] + xbp[3][h][c];
      atomicAdd(&xbsum[(b * 4 + h) * 256 + c], s);
    }
  } else if (bx_ < 1088) {
    // ---- prep_w: Wkh = f16(Wk); Wogh = f16(Wo * g) ----
    int i = (bx_ - 1024) * 256 + t;
#pragma unroll
    for (int j = 0; j < 4; ++j) {
      int idx = i + j * 16384;
      Wkh[idx] = (f16)Wk[idx];
      Wogh[idx] = (f16)(Wo[idx] * g[idx & 255]);
    }
  } else {
    // ---- fold_M: M[b][(h,d)][c] = 0.95 * S[b,h] @ Wq_h ----
    int idx = bx_ - 1088;          // [0,512)
    const int bh = idx >> 3;       // 0..63
    const int dq = idx & 7;        // 0..7
    const int h = bh & 3;
    const float* Sp = S + (size_t)bh * 4096 + dq * 8 * 64;
    const float* Wp = Wq + (size_t)h * 64 * 256 + t;
    float m[8] = {};
#pragma unroll 4
    for (int e = 0; e < 64; ++e) {
      float wv = Wp[e * 256];
#pragma unroll
      for (int dd = 0; dd < 8; ++dd) m[dd] += Sp[dd * 64 + e] * wv;
    }
    f16* Mb = M + (size_t)(bh >> 2) * 65536;
#pragma unroll
    for (int dd = 0; dd < 8; ++dd)
      Mb[(size_t)(h * 64 + dq * 8 + dd) * 256 + t] = (f16)(0.95f * m[dd]);
  }
}

// ---------------- k-GEMM (gload_lds staging) + elu/L2norm/col-sums --------
__global__ __launch_bounds__(256) void kgemm_h(
    const f16* __restrict__ xh, const f16* __restrict__ Wkh,
    const float* __restrict__ betaArr,
    float* __restrict__ ksum, float* __restrict__ kbsum) {
  __shared__ union {
    struct { f16 A[128][64]; f16 B[128][64]; } s;  // 32 KB staging
    f16 K[128][128];                               // 32 KB epilogue tile
  } u;
  __shared__ float bstage[2][128];
  const int t = threadIdx.x;
  const int m0 = blockIdx.y * 128;
  const int n0 = blockIdx.x * 128;
  const int b = m0 >> 12;
  const int wave = t >> 6, lane = t & 63;
  const int wm = (wave >> 1) * 64, wn = (wave & 1) * 64;
  const int fr = lane & 15, fq = lane >> 4;
  const int fr7 = fr & 7;
  const int srow = lane >> 3;
  const int sc = (lane & 7) ^ srow;
  {
    int hh = t >> 7, r = t & 127;
    bstage[hh][r] =
        betaArr[((size_t)(b * 4 + (n0 >> 6) + hh) << 12) + (m0 & 4095) + r];
  }
  const char* Ab = (const char*)&u.s.A[0][0];
  const char* Bb = (const char*)&u.s.B[0][0];
  f32x4 acc[4][4] = {};
#pragma unroll 1
  for (int kt = 0; kt < 4; ++kt) {
    const int k0 = kt * 64;
#pragma unroll
    for (int j = 0; j < 4; ++j) {
      int c = j * 4 + wave;
      int row = c * 8 + srow;
      gload16(xh + (size_t)(m0 + row) * 256 + k0 + sc * 8, &u.s.A[0][0] + c * 512);
      gload16(Wkh + (size_t)(n0 + row) * 256 + k0 + sc * 8, &u.s.B[0][0] + c * 512);
    }
    __syncthreads();
#pragma unroll
    for (int ks = 0; ks < 2; ++ks) {
      const int p = ((ks * 4 + fq) ^ fr7) << 4;
      f16x8 afr[4], bfr[4];
#pragma unroll
      for (int mi = 0; mi < 4; ++mi)
        afr[mi] = *(const f16x8*)(Ab + (wm + mi * 16 + fr) * 128 + p);
#pragma unroll
      for (int ni = 0; ni < 4; ++ni)
        bfr[ni] = *(const f16x8*)(Bb + (wn + ni * 16 + fr) * 128 + p);
#pragma unroll
      for (int mi = 0; mi < 4; ++mi)
#pragma unroll
        for (int ni = 0; ni < 4; ++ni)
          acc[mi][ni] = __builtin_amdgcn_mfma_f32_16x16x32_f16(
              afr[mi], bfr[ni], acc[mi][ni], 0, 0, 0);
    }
    __syncthreads();
  }
#pragma unroll
  for (int mi = 0; mi < 4; ++mi)
#pragma unroll
    for (int rr = 0; rr < 4; ++rr) {
      float s = 0.f;
#pragma unroll
      for (int ni = 0; ni < 4; ++ni) {
        float v = acc[mi][ni][rr];
        v = v > 0.f ? v + 1.f : __expf(v);
        acc[mi][ni][rr] = v;
        s += v * v;
      }
#pragma unroll
      for (int off = 1; off < 16; off <<= 1) s += __shfl_xor(s, off);
      float inv = 1.f / (sqrtf(s) + 1e-6f);
#pragma unroll
      for (int ni = 0; ni < 4; ++ni) acc[mi][ni][rr] *= inv;
    }
#pragma unroll
  for (int mi = 0; mi < 4; ++mi)
#pragma unroll
    for (int ni = 0; ni < 4; ++ni)
#pragma unroll
      for (int rr = 0; rr < 4; ++rr)
        u.K[wm + mi * 16 + fq * 4 + rr][wn + ni * 16 + fr] = (f16)acc[mi][ni][rr];
  __syncthreads();
  if (t < 128) {
    const int c = t, hl = c >> 6;
    float sk = 0.f, skb = 0.f;
#pragma unroll 4
    for (int r = 0; r < 128; ++r) {
      float v = (float)u.K[r][c];
      float be = bstage[hl][r];
      sk += v;
      skb += be * v;
    }
    int gh = b * 4 + (n0 >> 6) + hl;
    atomicAdd(&ksum[gh * 64 + (c & 63)], sk);
    atomicAdd(&kbsum[gh * 64 + (c & 63)], skb);
  }
}

// ---------------- fused y+out GEMM (R16, verified) ----------------
__global__ __launch_bounds__(256) void yogemm_h(
    const f16* __restrict__ xh, const f16* __restrict__ M,
    const f16* __restrict__ Wogh, float* __restrict__ out) {
  __shared__ f16 Bst[256 * 64];   // 32 KB: M-tile (ph1) / Wog-tile (ph2)
  __shared__ f16 Ast[64 * 64];    // 8 KB: xh-tile (ph1)
  __shared__ f16 yl[64 * 256];    // 32 KB: normalized y, chunk^=(row&7)
  __shared__ float ssq[4][64];
  __shared__ float rs_l[64];
  const int t = threadIdx.x;
  const int m0 = blockIdx.x * 64;
  const int b = m0 >> 12;
  const f16* Mb = M + (size_t)b * 65536;
  const int wave = t >> 6, lane = t & 63;
  const int wn = wave * 64;
  const int fr = lane & 15, fq = lane >> 4;
  const int fr7 = fr & 7;
  const int srow = lane >> 3;
  const int sc = (lane & 7) ^ srow;
  const char* Ab = (const char*)Ast;
  const char* Bb = (const char*)Bst;
  f32x4 acc[4][4] = {};
  // ---- phase 1: y = xh[m0:m0+64,:] @ M^T ----
#pragma unroll 1
  for (int kt = 0; kt < 4; ++kt) {
    const int k0 = kt * 64;
#pragma unroll
    for (int j = 0; j < 2; ++j) {
      int c = j * 4 + wave;
      int row = c * 8 + srow;
      gload16(xh + (size_t)(m0 + row) * 256 + k0 + sc * 8, Ast + c * 512);
    }
#pragma unroll
    for (int j = 0; j < 8; ++j) {
      int c = j * 4 + wave;
      int row = c * 8 + srow;
      gload16(Mb + (size_t)row * 256 + k0 + sc * 8, Bst + c * 512);
    }
    __syncthreads();
    __builtin_amdgcn_s_setprio(1);
#pragma unroll
    for (int ks = 0; ks < 2; ++ks) {
      const int p = ((ks * 4 + fq) ^ fr7) << 4;
      f16x8 afr[4], bfr[4];
#pragma unroll
      for (int mi = 0; mi < 4; ++mi)
        afr[mi] = *(const f16x8*)(Ab + (mi * 16 + fr) * 128 + p);
#pragma unroll
      for (int ni = 0; ni < 4; ++ni)
        bfr[ni] = *(const f16x8*)(Bb + (wn + ni * 16 + fr) * 128 + p);
#pragma unroll
      for (int mi = 0; mi < 4; ++mi)
#pragma unroll
        for (int ni = 0; ni < 4; ++ni)
          acc[mi][ni] = __builtin_amdgcn_mfma_f32_16x16x32_f16(
              afr[mi], bfr[ni], acc[mi][ni], 0, 0, 0);
    }
    __builtin_amdgcn_s_setprio(0);
    __syncthreads();
  }
  // ---- prefetch phase-2 kt=0 Wog tile (Bst free past final barrier) ----
#pragma unroll
  for (int j = 0; j < 8; ++j) {
    int c = j * 4 + wave;
    int row = c * 8 + srow;
    gload16(Wogh + (size_t)row * 256 + sc * 8, Bst + c * 512);
  }
  // ---- rowssq across 4 waves ----
#pragma unroll
  for (int mi = 0; mi < 4; ++mi)
#pragma unroll
    for (int rr = 0; rr < 4; ++rr) {
      float s = 0.f;
#pragma unroll
      for (int ni = 0; ni < 4; ++ni) {
        float v = acc[mi][ni][rr];
        s += v * v;
      }
#pragma unroll
      for (int off = 1; off < 16; off <<= 1) s += __shfl_xor(s, off);
      if (fr == 0) ssq[wave][mi * 16 + fq * 4 + rr] = s;
    }
  __syncthreads();
  if (t < 64)
    rs_l[t] = rsqrtf((ssq[0][t] + ssq[1][t] + ssq[2][t] + ssq[3][t]) *
                         (1.f / 256.f) +
                     1e-6f);
  __syncthreads();
  // ---- normalize + write swizzled f16 y-tile ----
#pragma unroll
  for (int mi = 0; mi < 4; ++mi)
#pragma unroll
    for (int rr = 0; rr < 4; ++rr) {
      int row = mi * 16 + fq * 4 + rr;
      float rs = rs_l[row];
      int r7 = row & 7;
#pragma unroll
      for (int ni = 0; ni < 4; ++ni) {
        int col = wn + ni * 16 + fr;
        int idx = row * 256 + ((((col >> 3) ^ r7) << 3) | (col & 7));
        yl[idx] = (f16)(rs * acc[mi][ni][rr]);
      }
    }
  __syncthreads();
  // ---- phase 2: out = yhat @ Wog^T (kt=0 tile already staged) ----
#pragma unroll
  for (int mi = 0; mi < 4; ++mi)
#pragma unroll
    for (int ni = 0; ni < 4; ++ni) acc[mi][ni] = (f32x4){0.f, 0.f, 0.f, 0.f};
#pragma unroll 1
  for (int kt = 0; kt < 4; ++kt) {
    if (kt > 0) {
      const int k0 = kt * 64;
#pragma unroll
      for (int j = 0; j < 8; ++j) {
        int c = j * 4 + wave;
        int row = c * 8 + srow;
        gload16(Wogh + (size_t)row * 256 + k0 + sc * 8, Bst + c * 512);
      }
      __syncthreads();
    }
    __builtin_amdgcn_s_setprio(1);
#pragma unroll
    for (int ks = 0; ks < 2; ++ks) {
      const int p = ((ks * 4 + fq) ^ fr7) << 4;
      f16x8 afr[4], bfr[4];
#pragma unroll
      for (int mi = 0; mi < 4; ++mi) {
        int row = mi * 16 + fr;
        int chunk = ((kt * 8 + ks * 4 + fq) ^ (row & 7)) << 4;
        afr[mi] = *(const f16x8*)((const char*)yl + row * 512 + chunk);
      }
#pragma unroll
      for (int ni = 0; ni < 4; ++ni)
        bfr[ni] = *(const f16x8*)(Bb + (wn + ni * 16 + fr) * 128 + p);
#pragma unroll
      for (int mi = 0; mi < 4; ++mi)
#pragma unroll
        for (int ni = 0; ni < 4; ++ni)
          acc[mi][ni] = __builtin_amdgcn_mfma_f32_16x16x32_f16(
              afr[mi], bfr[ni], acc[mi][ni], 0, 0, 0);
    }
    __builtin_amdgcn_s_setprio(0);
    __syncthreads();
  }
#pragma unroll
  for (int mi = 0; mi < 4; ++mi)
#pragma unroll
    for (int ni = 0; ni < 4; ++ni)
#pragma unroll
      for (int rr = 0; rr < 4; ++rr) {
        int row = m0 + mi * 16 + fq * 4 + rr;
        int col = wn + ni * 16 + fr;
        out[(size_t)row * 256 + col] = acc[mi][ni][rr];
      }
}

// ================= R9 fallback path (fp32 staging) =================
__global__ __launch_bounds__(256) void beta_xbsum(
    const float* __restrict__ x, const float* __restrict__ Wb,
    float* __restrict__ betaArr, float* __restrict__ xbsum) {
  const int t = threadIdx.x;
  const int wave = t >> 6, lane = t & 63;
  const int b = blockIdx.x >> 6;
  const int tile = blockIdx.x & 63;
  float4 wb[4];
#pragma unroll
  for (int h = 0; h < 4; ++h) wb[h] = *(const float4*)(Wb + h * 256 + lane * 4);
  float xacc[4][4] = {};
  const size_t rowbase = (size_t)b * 4096 + tile * 64;
  __shared__ float bsh[4][64];
  float4 xv = *(const float4*)(x + (rowbase + wave) * 256 + lane * 4);
#pragma unroll 2
  for (int i = 0; i < 16; ++i) {
    int r = i * 4 + wave;
    float4 nx = xv;
    if (i < 15)
      nx = *(const float4*)(x + (rowbase + r + 4) * 256 + lane * 4);
#pragma unroll
    for (int h = 0; h < 4; ++h) {
      float s = xv.x * wb[h].x + xv.y * wb[h].y + xv.z * wb[h].z + xv.w * wb[h].w;
#pragma unroll
      for (int off = 32; off; off >>= 1) s += __shfl_xor(s, off);
      float bh = 1.f / (1.f + __expf(-s));
      if (lane == h) bsh[h][r] = bh;
      xacc[h][0] += bh * xv.x; xacc[h][1] += bh * xv.y;
      xacc[h][2] += bh * xv.z; xacc[h][3] += bh * xv.w;
    }
    xv = nx;
  }
  __shared__ float xbp[4][4][256];
#pragma unroll
  for (int h = 0; h < 4; ++h)
#pragma unroll
    for (int j = 0; j < 4; ++j) xbp[wave][h][lane * 4 + j] = xacc[h][j];
  __syncthreads();
  {
    int h = t >> 6, r = t & 63;
    betaArr[((size_t)(b * 4 + h) << 12) + tile * 64 + r] = bsh[h][r];
  }
  for (int idx = t; idx < 1024; idx += 256) {
    int h = idx >> 8, c = idx & 255;
    float s = xbp[0][h][c] + xbp[1][h][c] + xbp[2][h][c] + xbp[3][h][c];
    atomicAdd(&xbsum[(b * 4 + h) * 256 + c], s);
  }
}

__global__ __launch_bounds__(256) void kgemm_sums(
    const float* __restrict__ x, const float* __restrict__ Wk,
    const float* __restrict__ betaArr,
    float* __restrict__ ksum, float* __restrict__ kbsum) {
  __shared__ union {
    struct { f16 A[128][72]; f16 B[128][72]; } s;
    f16 K[128][132];
  } u;
  __shared__ float bstage[2][128];
  const int t = threadIdx.x;
  const int m0 = blockIdx.y * 128;
  const int n0 = blockIdx.x * 128;
  const int b = m0 >> 12;
  const int wave = t >> 6, lane = t & 63;
  const int wm = (wave >> 1) * 64, wn = (wave & 1) * 64;
  const int fr = lane & 15, fq = lane >> 4;
  {
    int hh = t >> 7, r = t & 127;
    bstage[hh][r] =
        betaArr[((size_t)(b * 4 + (n0 >> 6) + hh) << 12) + (m0 & 4095) + r];
  }
  f32x4 acc[4][4] = {};
#pragma unroll 1
  for (int kt = 0; kt < 4; ++kt) {
    const int k0 = kt * 64;
#pragma unroll
    for (int i = 0; i < 4; ++i) {
      int id = i * 256 + t;
      int row = id >> 3, cc = id & 7;
      *(f16x8*)&u.s.A[row][cc * 8] =
          cvt8(x + (size_t)(m0 + row) * 256 + k0 + cc * 8);
      *(f16x8*)&u.s.B[row][cc * 8] =
          cvt8(Wk + (size_t)(n0 + row) * 256 + k0 + cc * 8);
    }
    __syncthreads();
#pragma unroll
    for (int ks = 0; ks < 2; ++ks) {
      f16x8 afr[4], bfr[4];
#pragma unroll
      for (int mi = 0; mi < 4; ++mi)
        afr[mi] = *(const f16x8*)&u.s.A[wm + mi * 16 + fr][ks * 32 + fq * 8];
#pragma unroll
      for (int ni = 0; ni < 4; ++ni)
        bfr[ni] = *(const f16x8*)&u.s.B[wn + ni * 16 + fr][ks * 32 + fq * 8];
#pragma unroll
      for (int mi = 0; mi < 4; ++mi)
#pragma unroll
        for (int ni = 0; ni < 4; ++ni)
          acc[mi][ni] = __builtin_amdgcn_mfma_f32_16x16x32_f16(
              afr[mi], bfr[ni], acc[mi][ni], 0, 0, 0);
    }
    __syncthreads();
  }
#pragma unroll
  for (int mi = 0; mi < 4; ++mi)
#pragma unroll
    for (int rr = 0; rr < 4; ++rr) {
      float s = 0.f;
#pragma unroll
      for (int ni = 0; ni < 4; ++ni) {
        float v = acc[mi][ni][rr];
        v = v > 0.f ? v + 1.f : __expf(v);
        acc[mi][ni][rr] = v;
        s += v * v;
      }
#pragma unroll
      for (int off = 1; off < 16; off <<= 1) s += __shfl_xor(s, off);
      float inv = 1.f / (sqrtf(s) + 1e-6f);
#pragma unroll
      for (int ni = 0; ni < 4; ++ni) acc[mi][ni][rr] *= inv;
    }
#pragma unroll
  for (int mi = 0; mi < 4; ++mi)
#pragma unroll
    for (int ni = 0; ni < 4; ++ni)
#pragma unroll
      for (int rr = 0; rr < 4; ++rr)
        u.K[wm + mi * 16 + fq * 4 + rr][wn + ni * 16 + fr] = (f16)acc[mi][ni][rr];
  __syncthreads();
  if (t < 128) {
    const int c = t, hl = c >> 6;
    float sk = 0.f, skb = 0.f;
#pragma unroll 4
    for (int r = 0; r < 128; ++r) {
      float v = (float)u.K[r][c];
      float be = bstage[hl][r];
      sk += v;
      skb += be * v;
    }
    int gh = b * 4 + (n0 >> 6) + hl;
    atomicAdd(&ksum[gh * 64 + (c & 63)], sk);
    atomicAdd(&kbsum[gh * 64 + (c & 63)], skb);
  }
}

__global__ __launch_bounds__(256) void fold_M(
    const float* __restrict__ S, const float* __restrict__ Wq,
    f16* __restrict__ M) {
  const int bh = blockIdx.y;
  const int dq = blockIdx.x;
  const int h = bh & 3;
  const int t = threadIdx.x;
  const float* Sp = S + (size_t)bh * 4096 + dq * 8 * 64;
  const float* Wp = Wq + (size_t)h * 64 * 256 + t;
  float m[8] = {};
#pragma unroll 4
  for (int e = 0; e < 64; ++e) {
    float wv = Wp[e * 256];
#pragma unroll
    for (int dd = 0; dd < 8; ++dd) m[dd] += Sp[dd * 64 + e] * wv;
  }
  f16* Mb = M + (size_t)(bh >> 2) * 65536;
#pragma unroll
  for (int dd = 0; dd < 8; ++dd)
    Mb[(size_t)(h * 64 + dq * 8 + dd) * 256 + t] = (f16)(0.95f * m[dd]);
}

__global__ __launch_bounds__(256) void ygemm_ssq(
    const float* __restrict__ x, int m_base, const f16* __restrict__ M,
    f16* __restrict__ y, float* __restrict__ rowssq) {
  __shared__ f16 As[128][72];
  __shared__ f16 Bs[128][72];
  const int t = threadIdx.x;
  const int m0 = blockIdx.y * 128;
  const int n0 = blockIdx.x * 128;
  const int b = (m_base + m0) >> 12;
  const f16* Mb = M + (size_t)b * 65536;
  const int wave = t >> 6, lane = t & 63;
  const int wm = (wave >> 1) * 64, wn = (wave & 1) * 64;
  const int fr = lane & 15, fq = lane >> 4;
  f32x4 acc[4][4] = {};
#pragma unroll 1
  for (int kt = 0; kt < 4; ++kt) {
    const int k0 = kt * 64;
#pragma unroll
    for (int i = 0; i < 4; ++i) {
      int id = i * 256 + t;
      int row = id >> 3, cc = id & 7;
      *(f16x8*)&As[row][cc * 8] =
          cvt8(x + (size_t)(m_base + m0 + row) * 256 + k0 + cc * 8);
      *(uint4*)&Bs[row][cc * 8] =
          *(const uint4*)(Mb + (size_t)(n0 + row) * 256 + k0 + cc * 8);
    }
    __syncthreads();
#pragma unroll
    for (int ks = 0; ks < 2; ++ks) {
      f16x8 afr[4], bfr[4];
#pragma unroll
      for (int mi = 0; mi < 4; ++mi)
        afr[mi] = *(const f16x8*)&As[wm + mi * 16 + fr][ks * 32 + fq * 8];
#pragma unroll
      for (int ni = 0; ni < 4; ++ni)
        bfr[ni] = *(const f16x8*)&Bs[wn + ni * 16 + fr][ks * 32 + fq * 8];
#pragma unroll
      for (int mi = 0; mi < 4; ++mi)
#pragma unroll
        for (int ni = 0; ni < 4; ++ni)
          acc[mi][ni] = __builtin_amdgcn_mfma_f32_16x16x32_f16(
              afr[mi], bfr[ni], acc[mi][ni], 0, 0, 0);
    }
    __syncthreads();
  }
#pragma unroll
  for (int mi = 0; mi < 4; ++mi)
#pragma unroll
    for (int rr = 0; rr < 4; ++rr) {
      float s = 0.f;
#pragma unroll
      for (int ni = 0; ni < 4; ++ni) {
        float v = acc[mi][ni][rr];
        s += v * v;
        int row = m0 + wm + mi * 16 + fq * 4 + rr;
        int col = n0 + wn + ni * 16 + fr;
        y[(size_t)row * 256 + col] = (f16)v;
      }
#pragma unroll
      for (int off = 1; off < 16; off <<= 1) s += __shfl_xor(s, off);
      if (fr == 0)
        atomicAdd(&rowssq[m0 + wm + mi * 16 + fq * 4 + rr], s);
    }
}

__global__ __launch_bounds__(256) void ogemm_scaled(
    const f16* __restrict__ y, const float* __restrict__ rowssq,
    const float* __restrict__ g_rms, const float* __restrict__ Wo,
    float* __restrict__ out, int m_base) {
  __shared__ f16 As[128][72];
  __shared__ f16 Bs[128][72];
  const int t = threadIdx.x;
  const int m0 = blockIdx.y * 128;
  const int n0 = blockIdx.x * 128;
  const int wave = t >> 6, lane = t & 63;
  const int wm = (wave >> 1) * 64, wn = (wave & 1) * 64;
  const int fr = lane & 15, fq = lane >> 4;
  f32x4 acc[4][4] = {};
#pragma unroll 1
  for (int kt = 0; kt < 4; ++kt) {
    const int k0 = kt * 64;
#pragma unroll
    for (int i = 0; i < 4; ++i) {
      int id = i * 256 + t;
      int row = id >> 3, cc = id & 7;
      float rs = rsqrtf(rowssq[m0 + row] * (1.f / 256.f) + 1e-6f);
      const f16* yp = y + (size_t)(m0 + row) * 256 + k0 + cc * 8;
      const float* gp = g_rms + k0 + cc * 8;
      f16x8 a;
#pragma unroll
      for (int j = 0; j < 8; ++j) a[j] = (f16)((float)yp[j] * rs * gp[j]);
      *(f16x8*)&As[row][cc * 8] = a;
      *(f16x8*)&Bs[row][cc * 8] =
          cvt8(Wo + (size_t)(n0 + row) * 256 + k0 + cc * 8);
    }
    __syncthreads();
#pragma unroll
    for (int ks = 0; ks < 2; ++ks) {
      f16x8 afr[4], bfr[4];
#pragma unroll
      for (int mi = 0; mi < 4; ++mi)
        afr[mi] = *(const f16x8*)&As[wm + mi * 16 + fr][ks * 32 + fq * 8];
#pragma unroll
      for (int ni = 0; ni < 4; ++ni)
        bfr[ni] = *(const f16x8*)&Bs[wn + ni * 16 + fr][ks * 32 + fq * 8];
#pragma unroll
      for (int mi = 0; mi < 4; ++mi)
#pragma unroll
        for (int ni = 0; ni < 4; ++ni)
          acc[mi][ni] = __builtin_amdgcn_mfma_f32_16x16x32_f16(
              afr[mi], bfr[ni], acc[mi][ni], 0, 0, 0);
    }
    __syncthreads();
  }
#pragma unroll
  for (int mi = 0; mi < 4; ++mi)
#pragma unroll
    for (int ni = 0; ni < 4; ++ni)
#pragma unroll
      for (int rr = 0; rr < 4; ++rr) {
        int row = m_base + m0 + wm + mi * 16 + fq * 4 + rr;
        int col = n0 + wn + ni * 16 + fr;
        out[(size_t)row * 256 + col] = acc[mi][ni][rr];
      }
}

// ---------------- finalize S ----------------
__global__ __launch_bounds__(256) void finalize_S(
    const float* __restrict__ S, const float* __restrict__ Wv,
    const float* __restrict__ xbsum, const float* __restrict__ ksum,
    const float* __restrict__ kbsum, float* __restrict__ Sout) {
  const int bh = blockIdx.x;
  const int h = bh & 3;
  const int t = threadIdx.x;
  const int wave = t >> 6, lane = t & 63;
  __shared__ float xb[256], kb[64], key[64], errv[64];
  xb[t] = xbsum[bh * 256 + t];
  if (t < 64) {
    kb[t] = kbsum[bh * 64 + t];
    key[t] = ksum[bh * 64 + t] * (1.f / 4096.f);
  }
  __syncthreads();
#pragma unroll 1
  for (int ri = 0; ri < 16; ++ri) {
    int i = wave * 16 + ri;
    float4 wv4 = *(const float4*)(Wv + (size_t)(h * 64 + i) * 256 + lane * 4);
    float4 xb4 = *(const float4*)(&xb[lane * 4]);
    float s = wv4.x * xb4.x + wv4.y * xb4.y + wv4.z * xb4.z + wv4.w * xb4.w;
    s -= 0.95f * S[(size_t)bh * 4096 + i * 64 + lane] * kb[lane];
#pragma unroll
    for (int off = 32; off; off >>= 1) s += __shfl_xor(s, off);
    if (lane == 0) errv[i] = s * (1.f / 4096.f);
  }
  __syncthreads();
  for (int idx = t; idx < 4096; idx += 256) {
    int i = idx >> 6, j = idx & 63;
    float v = 0.95f * S[(size_t)bh * 4096 + idx] + errv[i] * key[j];
    Sout[(size_t)bh * 4096 + idx] = fminf(10.f, fmaxf(-10.f, v));
  }
}

extern "C" void kernel_launch(void* const* d_in, const int* in_sizes, int n_in,
                              void* d_out, int out_size, void* d_ws, size_t ws_size,
                              hipStream_t stream) {
  const float* x  = (const float*)d_in[0];
  const float* S  = (const float*)d_in[1];
  const float* Wq = (const float*)d_in[2];
  const float* Wk = (const float*)d_in[3];
  const float* Wv = (const float*)d_in[4];
  const float* Wb = (const float*)d_in[5];
  const float* Wo = (const float*)d_in[6];
  const float* g  = (const float*)d_in[7];

  char* w = (char*)d_ws;
  float* betaArr = (float*)w;                    // 1,048,576 B
  f16*   M       = (f16*)(w + 1048576);          // 2,097,152 B
  f16*   y       = (f16*)(w + 3145728);          // 16,777,216 B (fallback only)
  float* rowssq  = (float*)(w + 19922944);       // 262,144 B (fallback only)
  float* xbsum   = (float*)(w + 20185088);       // 65,536 B
  float* ksum    = (float*)(w + 20250624);       // 16,384 B
  float* kbsum   = (float*)(w + 20267008);       // 16,384 B
  f16*   xh      = (f16*)(w + 20283392);         // 33,554,432 B (65536x256)
  f16*   Wkh     = (f16*)(w + 53837824);         // 131,072 B
  f16*   Wogh    = (f16*)(w + 53968896);         // 131,072 B
  const size_t WS_NEED = 54099968ull;

  float* out  = (float*)d_out;                   // [16,4096,256] fp32
  float* Sout = out + (size_t)16 * 4096 * 256;   // [16,4,64,64]  fp32

  if (ws_size >= WS_NEED) {
    hipMemsetAsync(w + 20185088, 0, 98304, stream);  // xbsum..kbsum
    prep_beta_fold<<<1600, 256, 0, stream>>>(x, S, Wq, Wk, Wo, Wb, g,
                                             betaArr, xbsum, xh, Wkh, Wogh, M);
    kgemm_h<<<dim3(2, 512), 256, 0, stream>>>(xh, Wkh, betaArr, ksum, kbsum);
    yogemm_h<<<1024, 256, 0, stream>>>(xh, M, Wogh, out);
  } else {
    hipMemsetAsync(w + 19922944, 0, 360448, stream);  // rowssq..kbsum
    beta_xbsum<<<1024, 256, 0, stream>>>(x, Wb, betaArr, xbsum);
    kgemm_sums<<<dim3(2, 512), 256, 0, stream>>>(x, Wk, betaArr, ksum, kbsum);
    fold_M<<<dim3(8, 64), 256, 0, stream>>>(S, Wq, M);
    for (int half = 0; half < 2; ++half) {
      int m_base = half * 32768;
      ygemm_ssq<<<dim3(2, 256), 256, 0, stream>>>(x, m_base, M, y,
                                                  rowssq + half * 32768);
      ogemm_scaled<<<dim3(2, 256), 256, 0, stream>>>(y, rowssq + half * 32768,
                                                     g, Wo, out, m_base);
    }
  }
  finalize_S<<<64, 256, 0, stream>>>(S, Wv, xbsum, ksum, kbsum, Sout);
}